// Round 10
// baseline (110.219 us; speedup 1.0000x reference)
//
#include <hip/hip_runtime.h>

#define NB1 64
#define B_RS 4

// workspace float offsets
#define W_K    0         // [64][1024] u64 packed (fkey<<32 | idx) -> 131072 slots
#define W_C    131072    // [64][1024] u32 counts
#define W_SB   196608    // [64][1024] f32 sum_b
#define W_SP   262144    // [64][1024] f32 p_sum
#define W_NS   327680    // [64][8] noise (cnt,sum per row)
#define A_CY0  328192    // 1024 float4 (-2x lo)
#define A_CY1  332288    // 1024 float4 (-2x hi)
#define A_LM   336384    // 1024 float2 (ck2+1e-6, cf)
#define A_EM   338432    // 1024 float4 (qa, psum, keym_bits, cf)
#define A_SBM  342528    // 1024 merged sum_b
#define A_NKM  343552    // 1024 u32 merged count
#define A_OC   344576    // 4 obj_cnt per row (+4 pad)
#define A_LSE  344584    // 8 x 1024 LSE slices
#define A_BIN  352776    // 64 reps x 8 row bins (att[4], rep[4])
#define A_TK   353288    // ticket (u32)

__device__ __forceinline__ unsigned fkey(float f) {
    unsigned u = __float_as_uint(f);
    return ((int)u < 0) ? ~u : (u | 0x80000000u);
}
__device__ __forceinline__ float fdec(unsigned k) {
    unsigned u = ((int)k < 0) ? (k & 0x7fffffffu) : ~k;
    return __uint_as_float(u);
}

// ---- P1: block-local LDS aggregation, private-slice flush, zero out-rep ----
__global__ __launch_bounds__(512) void k_p1(const float* __restrict__ beta,
                                            const int* __restrict__ asso,
                                            const int* __restrict__ rs,
                                            float* __restrict__ w,
                                            float* __restrict__ out, int N) {
    __shared__ unsigned long long sk[1024];
    __shared__ unsigned sc[1024];
    __shared__ float ssb[1024], ssp[1024];
    __shared__ float ns[8];
    int t = threadIdx.x, b = blockIdx.x;
    for (int j = t; j < 1024; j += 512) { sk[j] = 0ull; sc[j] = 0u; ssb[j] = 0.f; ssp[j] = 0.f; }
    if (t < 8) ns[t] = 0.f;
    int rs1 = rs[1], rs2 = rs[2], rs3 = rs[3];
    __syncthreads();
    for (int i = b * 512 + t; i < N; i += NB1 * 512) {
        float bv = beta[i];
        int a = asso[i];
        out[3 + N + i] = 0.f;   // zero rep-accumulator output region
        float bc = fminf(fmaxf(bv, 0.f), 0.999f);
        float ath = 0.5f * __logf(__fdividef(1.f + bc, 1.f - bc));
        float at2 = ath * ath;
        float pv = fmaxf(at2, 1e-6f);
        if (a >= 0) {
            unsigned long long pk = (((unsigned long long)fkey(bv)) << 32) | (unsigned)i;
            atomicMax(&sk[a], pk);
            atomicAdd(&sc[a], 1u);
            atomicAdd(&ssb[a], bv);
            atomicAdd(&ssp[a], pv);
        } else {
            int r = (i >= rs1) + (i >= rs2) + (i >= rs3);
            atomicAdd(&ns[2 * r], 1.f);
            atomicAdd(&ns[2 * r + 1], bv);
        }
    }
    __syncthreads();
    for (int j = t; j < 1024; j += 512) {
        ((unsigned long long*)w)[(b << 10) + j] = sk[j];
        ((unsigned*)w)[W_C + (b << 10) + j] = sc[j];
        w[W_SB + (b << 10) + j] = ssb[j];
        w[W_SP + (b << 10) + j] = ssp[j];
    }
    if (t < 8) w[W_NS + b * 8 + t] = ns[t];
}

// ---- M1: merge slices, build staged tables, obj_cnt, zero LSE/bins/ticket ----
__global__ __launch_bounds__(256) void k_m1(const float* __restrict__ beta,
                                            const float* __restrict__ coords,
                                            const int* __restrict__ rs,
                                            float* __restrict__ w) {
    __shared__ int oc0;
    int t = threadIdx.x, r = blockIdx.x;
    if (t == 0) oc0 = 0;
    int k = (r << 8) + t;
    unsigned long long k64 = 0ull;
    unsigned cnt = 0u;
    float sb = 0.f, sp = 0.f;
#pragma unroll 4
    for (int rp = 0; rp < NB1; ++rp) {
        unsigned long long v = ((const unsigned long long*)w)[(rp << 10) + k];
        k64 = v > k64 ? v : k64;
        cnt += ((const unsigned*)w)[W_C + (rp << 10) + k];
        sb += w[W_SB + (rp << 10) + k];
        sp += w[W_SP + (rp << 10) + k];
    }
    bool ov = cnt > 0u;
    int ai = (int)(unsigned)(k64 & 0xffffffffull);
    float4 x0 = ((const float4*)coords)[ai * 2];
    float4 x1 = ((const float4*)coords)[ai * 2 + 1];
    float ba = beta[ai];
    float bca = fminf(fmaxf(ba, 0.f), 0.999f);
    float ata = atanhf(bca);
    float qa = ov ? ata * ata + 0.1f : 0.f;
    float cf = qa / fmaxf((float)cnt, 1.f);
    ((float4*)(w + A_CY0))[k] = make_float4(-2.f * x0.x, -2.f * x0.y, -2.f * x0.z, -2.f * x0.w);
    ((float4*)(w + A_CY1))[k] = make_float4(-2.f * x1.x, -2.f * x1.y, -2.f * x1.z, -2.f * x1.w);
    float ck2 = x0.x * x0.x + x0.y * x0.y + x0.z * x0.z + x0.w * x0.w +
                x1.x * x1.x + x1.y * x1.y + x1.z * x1.z + x1.w * x1.w;
    ((float2*)(w + A_LM))[k] = make_float2(ck2 + 1e-6f, cf);
    ((float4*)(w + A_EM))[k] = make_float4(qa, sp, __uint_as_float((unsigned)(k64 >> 32)), cf);
    w[A_SBM + k] = sb;
    ((unsigned*)w)[A_NKM + k] = cnt;
    for (int j = t; j < 2048; j += 256) w[A_LSE + (r << 11) + j] = 0.f;
    if (r == 0) {
        for (int j = t; j < 512; j += 256) w[A_BIN + j] = 0.f;
        if (t == 0) ((unsigned*)w)[A_TK] = 0u;
    }
    __syncthreads();
    unsigned long long bal = __ballot(ov);
    if ((t & 63) == 0) atomicAdd(&oc0, __popcll(bal));
    __syncthreads();
    if (t == 0) w[A_OC + r] = (float)oc0;
}

// ---- P4: chunked repulsion (2pt/thread) + fused epilogue + last-block finale ----
__global__ __launch_bounds__(128) void k_p4(const float* __restrict__ beta,
                                            const float* __restrict__ coords,
                                            const int* __restrict__ asso,
                                            const int* __restrict__ rs,
                                            const float* __restrict__ wc,
                                            float* __restrict__ lse,
                                            float* __restrict__ bin,
                                            unsigned* __restrict__ tk,
                                            float* __restrict__ out, int N) {
    __shared__ float4 sY0[128], sY1[128];
    __shared__ float2 sLM[128];
    __shared__ float bins[8];
    __shared__ int sLast;
    int t = threadIdx.x, bid = blockIdx.x;
    int pc = bid >> 2, cc = bid & 3;
    int base = pc << 8;
    int rs1 = rs[1], rs2 = rs[2], rs3 = rs[3];
    int r0 = (base >= rs1) + (base >= rs2) + (base >= rs3);
    int lastp = min(base + 255, N - 1);
    int rl = (lastp >= rs1) + (lastp >= rs2) + (lastp >= rs3);
    const float4* cy0 = (const float4*)(wc + A_CY0);
    const float4* cy1 = (const float4*)(wc + A_CY1);
    const float2* lmt = (const float2*)(wc + A_LM);
    if (t < 64) {
        int k0 = (r0 << 8) + (cc << 6) + t;
        sY0[t] = cy0[k0]; sY1[t] = cy1[k0]; sLM[t] = lmt[k0];
    } else if (rl != r0) {
        int j = t - 64;
        int k1 = (rl << 8) + (cc << 6) + j;
        sY0[t] = cy0[k1]; sY1[t] = cy1[k1]; sLM[t] = lmt[k1];
    }
    if (t < 8) bins[t] = 0.f;
    __syncthreads();
    int i0 = base + 2 * t, i1 = i0 + 1;
    bool in0 = i0 < N, in1 = i1 < N;
    float att0 = 0.f, att1 = 0.f, rep0 = 0.f, rep1 = 0.f;
    int rr0 = r0, rr1 = r0;
    if (in0) {
        const float4* cp = (const float4*)(coords + (size_t)i0 * 8);
        float4 c00 = cp[0], c01 = cp[1], c10, c11;
        float cn20 = c00.x * c00.x + c00.y * c00.y + c00.z * c00.z + c00.w * c00.w +
                     c01.x * c01.x + c01.y * c01.y + c01.z * c01.z + c01.w * c01.w;
        float cn21 = 0.f;
        rr0 = (i0 >= rs1) + (i0 >= rs2) + (i0 >= rs3);
        if (in1) {
            c10 = cp[2]; c11 = cp[3];
            cn21 = c10.x * c10.x + c10.y * c10.y + c10.z * c10.z + c10.w * c10.w +
                   c11.x * c11.x + c11.y * c11.y + c11.z * c11.z + c11.w * c11.w;
            rr1 = (i1 >= rs1) + (i1 >= rs2) + (i1 >= rs3);
        }
        int s0 = (rr0 == r0) ? 0 : 64;
        int s1 = (rr1 == r0) ? 0 : 64;
        float acc0 = 0.f, acc1 = 0.f;
        if (in1 && s0 == s1) {
#pragma unroll 2
            for (int j = s0; j < s0 + 64; ++j) {
                float4 y0 = sY0[j];
                float4 y1 = sY1[j];
                float2 cm = sLM[j];
                float d0 = cn20 + cm.x, d1 = cn21 + cm.x;
                d0 = fmaf(y0.x, c00.x, d0); d1 = fmaf(y0.x, c10.x, d1);
                d0 = fmaf(y0.y, c00.y, d0); d1 = fmaf(y0.y, c10.y, d1);
                d0 = fmaf(y0.z, c00.z, d0); d1 = fmaf(y0.z, c10.z, d1);
                d0 = fmaf(y0.w, c00.w, d0); d1 = fmaf(y0.w, c10.w, d1);
                d0 = fmaf(y1.x, c01.x, d0); d1 = fmaf(y1.x, c11.x, d1);
                d0 = fmaf(y1.y, c01.y, d0); d1 = fmaf(y1.y, c11.y, d1);
                d0 = fmaf(y1.z, c01.z, d0); d1 = fmaf(y1.z, c11.z, d1);
                d0 = fmaf(y1.w, c01.w, d0); d1 = fmaf(y1.w, c11.w, d1);
                d0 = fmaxf(d0, 1e-6f); d1 = fmaxf(d1, 1e-6f);
                float v0 = fmaxf(1.f - sqrtf(d0), 0.f);
                float v1 = fmaxf(1.f - sqrtf(d1), 0.f);
                acc0 = fmaf(v0, cm.y, acc0);
                acc1 = fmaf(v1, cm.y, acc1);
            }
        } else {
#pragma unroll 2
            for (int j = s0; j < s0 + 64; ++j) {
                float4 y0 = sY0[j]; float4 y1 = sY1[j]; float2 cm = sLM[j];
                float d = cn20 + cm.x;
                d = fmaf(y0.x, c00.x, d); d = fmaf(y0.y, c00.y, d);
                d = fmaf(y0.z, c00.z, d); d = fmaf(y0.w, c00.w, d);
                d = fmaf(y1.x, c01.x, d); d = fmaf(y1.y, c01.y, d);
                d = fmaf(y1.z, c01.z, d); d = fmaf(y1.w, c01.w, d);
                d = fmaxf(d, 1e-6f);
                acc0 = fmaf(fmaxf(1.f - sqrtf(d), 0.f), cm.y, acc0);
            }
            if (in1) {
#pragma unroll 2
                for (int j = s1; j < s1 + 64; ++j) {
                    float4 y0 = sY0[j]; float4 y1 = sY1[j]; float2 cm = sLM[j];
                    float d = cn21 + cm.x;
                    d = fmaf(y0.x, c10.x, d); d = fmaf(y0.y, c10.y, d);
                    d = fmaf(y0.z, c10.z, d); d = fmaf(y0.w, c10.w, d);
                    d = fmaf(y1.x, c11.x, d); d = fmaf(y1.y, c11.y, d);
                    d = fmaf(y1.z, c11.z, d); d = fmaf(y1.w, c11.w, d);
                    d = fmaxf(d, 1e-6f);
                    acc1 = fmaf(fmaxf(1.f - sqrtf(d), 0.f), cm.y, acc1);
                }
            }
        }
        float2 b2; int2 a2;
        if (in1) { b2 = *(const float2*)(beta + i0); a2 = *(const int2*)(asso + i0); }
        else { b2.x = beta[i0]; b2.y = 0.f; a2.x = asso[i0]; a2.y = -1; }
#pragma unroll
        for (int p = 0; p < 2; ++p) {
            if (p && !in1) break;
            int i = p ? i1 : i0;
            float bv = p ? b2.y : b2.x;
            int aa = p ? a2.y : a2.x;
            float acc = p ? acc1 : acc0;
            float4 cA = p ? c10 : c00;
            float4 cB = p ? c11 : c01;
            float cn2 = p ? cn21 : cn20;
            int r = p ? rr1 : rr0;
            float bc = fminf(fmaxf(bv, 0.f), 0.999f);
            float ath = 0.5f * __logf(__fdividef(1.f + bc, 1.f - bc));
            float at2 = ath * ath;
            float q = at2 + 0.1f;
            if (cc == 0) {
                float attv = 0.f, pl = 0.f;
                if (aa >= 0) {
                    float4 y0 = cy0[aa], y1 = cy1[aa];
                    float4 em = ((const float4*)(wc + A_EM))[aa];
                    float d0 = cA.x + 0.5f * y0.x, d1 = cA.y + 0.5f * y0.y;
                    float d2 = cA.z + 0.5f * y0.z, d3 = cA.w + 0.5f * y0.w;
                    float d4 = cB.x + 0.5f * y1.x, d5 = cB.y + 0.5f * y1.y;
                    float d6 = cB.z + 0.5f * y1.z, d7 = cB.w + 0.5f * y1.w;
                    float dsq = d0 * d0 + d1 * d1 + d2 * d2 + d3 * d3 +
                                d4 * d4 + d5 * d5 + d6 * d6 + d7 * d7;
                    attv = q * em.x * dsq;
                    // own-term: bit-exact reconstruction of the staged ck2+1e-6
                    float yy = y0.x * y0.x + y0.y * y0.y + y0.z * y0.z + y0.w * y0.w +
                               y1.x * y1.x + y1.y * y1.y + y1.z * y1.z + y1.w * y1.w;
                    float d = cn2 + fmaf(0.25f, yy, 1e-6f);
                    d = fmaf(y0.x, cA.x, d); d = fmaf(y0.y, cA.y, d);
                    d = fmaf(y0.z, cA.z, d); d = fmaf(y0.w, cA.w, d);
                    d = fmaf(y1.x, cB.x, d); d = fmaf(y1.y, cB.y, d);
                    d = fmaf(y1.z, cB.z, d); d = fmaf(y1.w, cB.w, d);
                    d = fmaxf(d, 1e-6f);
                    acc -= fmaxf(1.f - sqrtf(d), 0.f) * em.w;
                    float m = fdec(__float_as_uint(em.z));
                    atomicAdd(&lse[((bid & 7) << 10) + aa], __expf((bv - m) * 1000.f));
                    float pv = fmaxf(at2, 1e-6f);
                    pl = pv / fmaxf(em.y, 1e-6f) / fmaxf(wc[A_OC + r], 1.f) * 0.25f;
                }
                float repc = q * acc;
                out[3 + i] = pl;
                atomicAdd(&out[3 + N + i], attv + repc);
                if (p) { att1 = attv; rep1 = repc; } else { att0 = attv; rep0 = repc; }
            } else {
                float repc = q * acc;
                atomicAdd(&out[3 + N + i], repc);
                if (p) rep1 = repc; else rep0 = repc;
            }
        }
    }
    // row-bin reduction
    {
        int rA = __shfl(rr0, 0);
        bool uni = __all(rr0 == rA) && __all(rr1 == rA);
        int lane = t & 63;
        if (uni) {
            float aS = att0 + att1, rS = rep0 + rep1;
#pragma unroll
            for (int o = 32; o; o >>= 1) { aS += __shfl_xor(aS, o); rS += __shfl_xor(rS, o); }
            if (lane == 0) { atomicAdd(&bins[rA], aS); atomicAdd(&bins[4 + rA], rS); }
        } else {
            if (in0) { atomicAdd(&bins[rr0], att0); atomicAdd(&bins[4 + rr0], rep0); }
            if (in1) { atomicAdd(&bins[rr1], att1); atomicAdd(&bins[4 + rr1], rep1); }
        }
    }
    __syncthreads();
    if (t < 8) atomicAdd(&bin[(bid & 63) * 8 + t], bins[t]);
    // last-block finale
    if (t == 0) {
        __threadfence();
        unsigned tkv = atomicAdd(tk, 1u);
        sLast = (tkv == gridDim.x - 1) ? 1 : 0;
    }
    __syncthreads();
    if (sLast) {
        __threadfence();
        __shared__ float sOP[4], sAR[8], sNS[8];
        if (t < 4) sOP[t] = 0.f;
        __syncthreads();
        if (t < 8) {
            float a = 0.f;
            for (int j = 0; j < 64; ++j) a += bin[j * 8 + t];
            sAR[t] = a;
        } else if (t < 16) {
            int s = t - 8;
            float a = 0.f;
            for (int b = 0; b < NB1; ++b) a += wc[W_NS + b * 8 + s];
            sNS[s] = a;
        }
        for (int k = t; k < 1024; k += 128) {
            unsigned cnt = ((const unsigned*)wc)[A_NKM + k];
            if (cnt > 0u) {
                float ls = 0.f;
#pragma unroll
                for (int rp = 0; rp < 8; ++rp) ls += lse[(rp << 10) + k];
                float4 em = ((const float4*)(wc + A_EM))[k];
                float m = fdec(__float_as_uint(em.z));
                float lsev = m + 0.001f * logf(ls + 1e-30f);
                float sbc = fminf(fmaxf(wc[A_SBM + k], 0.f), 1.f);
                atomicAdd(&sOP[k >> 8], (1.f - lsev) + (1.f - sbc));
            }
        }
        __syncthreads();
        if (t == 0) {
            float lv = 0.f, lr = 0.f, lb = 0.f;
            for (int r = 0; r < B_RS; ++r) {
                float len = (float)(rs[r + 1] - rs[r]);
                lv += sAR[r] / len;
                lr += sAR[4 + r] / len;
                float oc = wc[A_OC + r];
                lb += sOP[r] / fmaxf(oc, 1.f) + sNS[2 * r + 1] / fmaxf(sNS[2 * r], 1.f);
            }
            out[0] = lv * 0.25f;
            out[1] = lr * 0.25f;
            out[2] = lb * 0.25f;
        }
    }
}

extern "C" void kernel_launch(void* const* d_in, const int* in_sizes, int n_in,
                              void* d_out, int out_size, void* d_ws, size_t ws_size,
                              hipStream_t stream) {
    const float* beta = (const float*)d_in[0];
    const float* coords = (const float*)d_in[1];
    const int* asso = (const int*)d_in[2];
    const int* rs = (const int*)d_in[3];
    int N = in_sizes[0];
    float* w = (float*)d_ws;
    float* out = (float*)d_out;
    int npc = (N + 255) / 256;
    hipLaunchKernelGGL(k_p1, dim3(NB1), dim3(512), 0, stream, beta, asso, rs, w, out, N);
    hipLaunchKernelGGL(k_m1, dim3(4), dim3(256), 0, stream, beta, coords, rs, w);
    hipLaunchKernelGGL(k_p4, dim3(npc * 4), dim3(128), 0, stream, beta, coords, asso, rs,
                       w, w + A_LSE, w + A_BIN, (unsigned*)(w + A_TK), out, N);
}

// Round 11
// 93.570 us; speedup vs baseline: 1.1779x; 1.1779x over previous
//
#include <hip/hip_runtime.h>

#define NB1 64
#define B_RS 4

// workspace float offsets
#define W_K    0         // [64][1024] u64 packed (fkey<<32 | idx) -> 131072 slots
#define W_C    131072    // [64][1024] u32 counts
#define W_SB   196608    // [64][1024] f32 sum_b
#define W_SP   262144    // [64][1024] f32 p_sum
#define W_NS   327680    // [64][8] noise (cnt,sum per row)
#define A_CY0  328192    // 1024 float4 (-2x lo)
#define A_CY1  332288    // 1024 float4 (-2x hi)
#define A_LM   336384    // 1024 float2 (ck2+1e-6, cf)
#define A_EM   338432    // 1024 float4 (qa, psum, keym_bits, cf)
#define A_SBM  342528    // 1024 merged sum_b
#define A_NKM  343552    // 1024 u32 merged count
#define A_OC   344576    // 4 obj_cnt per row (+4 pad)
#define A_LSE  344584    // 8 x 1024 LSE slices
#define A_BIN  352776    // 64 reps x 8 row bins (att[4], rep[4])
#define A_TK   353288    // ticket (u32)

__device__ __forceinline__ unsigned fkey(float f) {
    unsigned u = __float_as_uint(f);
    return ((int)u < 0) ? ~u : (u | 0x80000000u);
}
__device__ __forceinline__ float fdec(unsigned k) {
    unsigned u = ((int)k < 0) ? (k & 0x7fffffffu) : ~k;
    return __uint_as_float(u);
}

// ---- P1: block-local LDS aggregation, private-slice flush ----
__global__ __launch_bounds__(512) void k_p1(const float* __restrict__ beta,
                                            const int* __restrict__ asso,
                                            const int* __restrict__ rs,
                                            float* __restrict__ w, int N) {
    __shared__ unsigned long long sk[1024];
    __shared__ unsigned sc[1024];
    __shared__ float ssb[1024], ssp[1024];
    __shared__ float ns[8];
    int t = threadIdx.x, b = blockIdx.x;
    for (int j = t; j < 1024; j += 512) { sk[j] = 0ull; sc[j] = 0u; ssb[j] = 0.f; ssp[j] = 0.f; }
    if (t < 8) ns[t] = 0.f;
    int rs1 = rs[1], rs2 = rs[2], rs3 = rs[3];
    __syncthreads();
    for (int i = b * 512 + t; i < N; i += NB1 * 512) {
        float bv = beta[i];
        int a = asso[i];
        float bc = fminf(fmaxf(bv, 0.f), 0.999f);
        float ath = 0.5f * __logf(__fdividef(1.f + bc, 1.f - bc));
        float at2 = ath * ath;
        float pv = fmaxf(at2, 1e-6f);
        if (a >= 0) {
            unsigned long long pk = (((unsigned long long)fkey(bv)) << 32) | (unsigned)i;
            atomicMax(&sk[a], pk);
            atomicAdd(&sc[a], 1u);
            atomicAdd(&ssb[a], bv);
            atomicAdd(&ssp[a], pv);
        } else {
            int r = (i >= rs1) + (i >= rs2) + (i >= rs3);
            atomicAdd(&ns[2 * r], 1.f);
            atomicAdd(&ns[2 * r + 1], bv);
        }
    }
    __syncthreads();
    for (int j = t; j < 1024; j += 512) {
        ((unsigned long long*)w)[(b << 10) + j] = sk[j];
        ((unsigned*)w)[W_C + (b << 10) + j] = sc[j];
        w[W_SB + (b << 10) + j] = ssb[j];
        w[W_SP + (b << 10) + j] = ssp[j];
    }
    if (t < 8) w[W_NS + b * 8 + t] = ns[t];
}

// ---- M1: merge slices, build staged tables, obj_cnt, zero LSE/bins/ticket ----
__global__ __launch_bounds__(256) void k_m1(const float* __restrict__ beta,
                                            const float* __restrict__ coords,
                                            const int* __restrict__ rs,
                                            float* __restrict__ w) {
    __shared__ int oc0;
    int t = threadIdx.x, r = blockIdx.x;
    if (t == 0) oc0 = 0;
    int k = (r << 8) + t;
    unsigned long long k64 = 0ull;
    unsigned cnt = 0u;
    float sb = 0.f, sp = 0.f;
#pragma unroll 4
    for (int rp = 0; rp < NB1; ++rp) {
        unsigned long long v = ((const unsigned long long*)w)[(rp << 10) + k];
        k64 = v > k64 ? v : k64;
        cnt += ((const unsigned*)w)[W_C + (rp << 10) + k];
        sb += w[W_SB + (rp << 10) + k];
        sp += w[W_SP + (rp << 10) + k];
    }
    bool ov = cnt > 0u;
    int ai = (int)(unsigned)(k64 & 0xffffffffull);
    float4 x0 = ((const float4*)coords)[ai * 2];
    float4 x1 = ((const float4*)coords)[ai * 2 + 1];
    float ba = beta[ai];
    float bca = fminf(fmaxf(ba, 0.f), 0.999f);
    float ata = atanhf(bca);
    float qa = ov ? ata * ata + 0.1f : 0.f;
    float cf = qa / fmaxf((float)cnt, 1.f);
    ((float4*)(w + A_CY0))[k] = make_float4(-2.f * x0.x, -2.f * x0.y, -2.f * x0.z, -2.f * x0.w);
    ((float4*)(w + A_CY1))[k] = make_float4(-2.f * x1.x, -2.f * x1.y, -2.f * x1.z, -2.f * x1.w);
    float ck2 = x0.x * x0.x + x0.y * x0.y + x0.z * x0.z + x0.w * x0.w +
                x1.x * x1.x + x1.y * x1.y + x1.z * x1.z + x1.w * x1.w;
    ((float2*)(w + A_LM))[k] = make_float2(ck2 + 1e-6f, cf);
    ((float4*)(w + A_EM))[k] = make_float4(qa, sp, __uint_as_float((unsigned)(k64 >> 32)), cf);
    w[A_SBM + k] = sb;
    ((unsigned*)w)[A_NKM + k] = cnt;
    for (int j = t; j < 2048; j += 256) w[A_LSE + (r << 11) + j] = 0.f;
    if (r == 0) {
        for (int j = t; j < 512; j += 256) w[A_BIN + j] = 0.f;
        if (t == 0) ((unsigned*)w)[A_TK] = 0u;
    }
    __syncthreads();
    unsigned long long bal = __ballot(ov);
    if ((t & 63) == 0) atomicAdd(&oc0, __popcll(bal));
    __syncthreads();
    if (t == 0) w[A_OC + r] = (float)oc0;
}

// ---- P4: 1-wave blocks, 2pt/thread, full-row stage, fused epilogue + finale ----
__global__ __launch_bounds__(64) void k_p4(const float* __restrict__ beta,
                                           const float* __restrict__ coords,
                                           const int* __restrict__ asso,
                                           const int* __restrict__ rs,
                                           const float* __restrict__ wc,
                                           float* __restrict__ lse,
                                           float* __restrict__ bin,
                                           unsigned* __restrict__ tk,
                                           float* __restrict__ out, int N) {
    __shared__ float4 sY0[512], sY1[512], sEM[512];
    __shared__ float2 sLM[512];
    __shared__ float sOC[4];
    __shared__ int sLast;
    int t = threadIdx.x, bid = blockIdx.x;
    int base = bid << 7;
    int rs1 = rs[1], rs2 = rs[2], rs3 = rs[3];
    int r0 = (base >= rs1) + (base >= rs2) + (base >= rs3);
    int lastp = min(base + 127, N - 1);
    int rl = (lastp >= rs1) + (lastp >= rs2) + (lastp >= rs3);
    const float4* cy0 = (const float4*)(wc + A_CY0);
    const float4* cy1 = (const float4*)(wc + A_CY1);
    const float2* lmt = (const float2*)(wc + A_LM);
    const float4* emt = (const float4*)(wc + A_EM);
#pragma unroll
    for (int j = t; j < 256; j += 64) {
        int k0 = (r0 << 8) + j;
        sY0[j] = cy0[k0]; sY1[j] = cy1[k0]; sLM[j] = lmt[k0]; sEM[j] = emt[k0];
    }
    if (rl != r0) {
#pragma unroll
        for (int j = t; j < 256; j += 64) {
            int k1 = (rl << 8) + j;
            sY0[256 + j] = cy0[k1]; sY1[256 + j] = cy1[k1];
            sLM[256 + j] = lmt[k1]; sEM[256 + j] = emt[k1];
        }
    }
    if (t < 4) sOC[t] = wc[A_OC + t];
    __syncthreads();
    int i0 = base + 2 * t, i1 = i0 + 1;
    bool in0 = i0 < N, in1 = i1 < N;
    float att0 = 0.f, att1 = 0.f, rep0 = 0.f, rep1 = 0.f;
    int rr0 = r0, rr1 = r0;
    if (in0) {
        const float4* cp = (const float4*)(coords + (size_t)i0 * 8);
        float4 c00 = cp[0], c01 = cp[1], c10, c11;
        float cn20 = c00.x * c00.x + c00.y * c00.y + c00.z * c00.z + c00.w * c00.w +
                     c01.x * c01.x + c01.y * c01.y + c01.z * c01.z + c01.w * c01.w;
        float cn21 = 0.f;
        rr0 = (i0 >= rs1) + (i0 >= rs2) + (i0 >= rs3);
        if (in1) {
            c10 = cp[2]; c11 = cp[3];
            cn21 = c10.x * c10.x + c10.y * c10.y + c10.z * c10.z + c10.w * c10.w +
                   c11.x * c11.x + c11.y * c11.y + c11.z * c11.z + c11.w * c11.w;
            rr1 = (i1 >= rs1) + (i1 >= rs2) + (i1 >= rs3);
        }
        int s0 = (rr0 == r0) ? 0 : 256;
        int s1 = (rr1 == r0) ? 0 : 256;
        float acc0 = 0.f, acc1 = 0.f;
        if (in1 && s0 == s1) {
#pragma unroll 2
            for (int j = s0; j < s0 + 256; ++j) {
                float4 y0 = sY0[j];
                float4 y1 = sY1[j];
                float2 cm = sLM[j];
                float d0 = cn20 + cm.x, d1 = cn21 + cm.x;
                d0 = fmaf(y0.x, c00.x, d0); d1 = fmaf(y0.x, c10.x, d1);
                d0 = fmaf(y0.y, c00.y, d0); d1 = fmaf(y0.y, c10.y, d1);
                d0 = fmaf(y0.z, c00.z, d0); d1 = fmaf(y0.z, c10.z, d1);
                d0 = fmaf(y0.w, c00.w, d0); d1 = fmaf(y0.w, c10.w, d1);
                d0 = fmaf(y1.x, c01.x, d0); d1 = fmaf(y1.x, c11.x, d1);
                d0 = fmaf(y1.y, c01.y, d0); d1 = fmaf(y1.y, c11.y, d1);
                d0 = fmaf(y1.z, c01.z, d0); d1 = fmaf(y1.z, c11.z, d1);
                d0 = fmaf(y1.w, c01.w, d0); d1 = fmaf(y1.w, c11.w, d1);
                d0 = fmaxf(d0, 1e-6f); d1 = fmaxf(d1, 1e-6f);
                float v0 = fmaxf(1.f - sqrtf(d0), 0.f);
                float v1 = fmaxf(1.f - sqrtf(d1), 0.f);
                acc0 = fmaf(v0, cm.y, acc0);
                acc1 = fmaf(v1, cm.y, acc1);
            }
        } else {
#pragma unroll 2
            for (int j = s0; j < s0 + 256; ++j) {
                float4 y0 = sY0[j]; float4 y1 = sY1[j]; float2 cm = sLM[j];
                float d = cn20 + cm.x;
                d = fmaf(y0.x, c00.x, d); d = fmaf(y0.y, c00.y, d);
                d = fmaf(y0.z, c00.z, d); d = fmaf(y0.w, c00.w, d);
                d = fmaf(y1.x, c01.x, d); d = fmaf(y1.y, c01.y, d);
                d = fmaf(y1.z, c01.z, d); d = fmaf(y1.w, c01.w, d);
                d = fmaxf(d, 1e-6f);
                acc0 = fmaf(fmaxf(1.f - sqrtf(d), 0.f), cm.y, acc0);
            }
            if (in1) {
#pragma unroll 2
                for (int j = s1; j < s1 + 256; ++j) {
                    float4 y0 = sY0[j]; float4 y1 = sY1[j]; float2 cm = sLM[j];
                    float d = cn21 + cm.x;
                    d = fmaf(y0.x, c10.x, d); d = fmaf(y0.y, c10.y, d);
                    d = fmaf(y0.z, c10.z, d); d = fmaf(y0.w, c10.w, d);
                    d = fmaf(y1.x, c11.x, d); d = fmaf(y1.y, c11.y, d);
                    d = fmaf(y1.z, c11.z, d); d = fmaf(y1.w, c11.w, d);
                    d = fmaxf(d, 1e-6f);
                    acc1 = fmaf(fmaxf(1.f - sqrtf(d), 0.f), cm.y, acc1);
                }
            }
        }
        float2 b2; int2 a2;
        if (in1) { b2 = *(const float2*)(beta + i0); a2 = *(const int2*)(asso + i0); }
        else { b2.x = beta[i0]; b2.y = 0.f; a2.x = asso[i0]; a2.y = -1; }
#pragma unroll
        for (int p = 0; p < 2; ++p) {
            if (p && !in1) break;
            int i = p ? i1 : i0;
            float bv = p ? b2.y : b2.x;
            int aa = p ? a2.y : a2.x;
            float acc = p ? acc1 : acc0;
            float4 cA = p ? c10 : c00;
            float4 cB = p ? c11 : c01;
            float cn2 = p ? cn21 : cn20;
            int r = p ? rr1 : rr0;
            float bc = fminf(fmaxf(bv, 0.f), 0.999f);
            float ath = 0.5f * __logf(__fdividef(1.f + bc, 1.f - bc));
            float at2 = ath * ath;
            float q = at2 + 0.1f;
            float attv = 0.f, pl = 0.f;
            if (aa >= 0) {
                int slot = (((aa >> 8) == r0) ? 0 : 256) + (aa & 255);
                float4 y0 = sY0[slot], y1 = sY1[slot];
                float2 cm = sLM[slot];
                float4 em = sEM[slot];
                float d0 = cA.x + 0.5f * y0.x, d1 = cA.y + 0.5f * y0.y;
                float d2 = cA.z + 0.5f * y0.z, d3 = cA.w + 0.5f * y0.w;
                float d4 = cB.x + 0.5f * y1.x, d5 = cB.y + 0.5f * y1.y;
                float d6 = cB.z + 0.5f * y1.z, d7 = cB.w + 0.5f * y1.w;
                float dsq = d0 * d0 + d1 * d1 + d2 * d2 + d3 * d3 +
                            d4 * d4 + d5 * d5 + d6 * d6 + d7 * d7;
                attv = q * em.x * dsq;
                // own-term: identical sequence to the loop body -> bit-exact
                float d = cn2 + cm.x;
                d = fmaf(y0.x, cA.x, d); d = fmaf(y0.y, cA.y, d);
                d = fmaf(y0.z, cA.z, d); d = fmaf(y0.w, cA.w, d);
                d = fmaf(y1.x, cB.x, d); d = fmaf(y1.y, cB.y, d);
                d = fmaf(y1.z, cB.z, d); d = fmaf(y1.w, cB.w, d);
                d = fmaxf(d, 1e-6f);
                acc -= fmaxf(1.f - sqrtf(d), 0.f) * cm.y;
                float m = fdec(__float_as_uint(em.z));
                atomicAdd(&lse[((bid & 7) << 10) + aa], __expf((bv - m) * 1000.f));
                float pv = fmaxf(at2, 1e-6f);
                pl = pv / fmaxf(em.y, 1e-6f) / fmaxf(sOC[r], 1.f) * 0.25f;
            }
            float repc = q * acc;
            out[3 + i] = pl;
            out[3 + N + i] = attv + repc;
            if (p) { att1 = attv; rep1 = repc; } else { att0 = attv; rep0 = repc; }
        }
    }
    // row-bin reduction (single wave)
    {
        int rA = __shfl(rr0, 0);
        bool uni = __all(rr0 == rA) && __all(rr1 == rA);
        if (uni) {
            float aS = att0 + att1, rS = rep0 + rep1;
#pragma unroll
            for (int o = 32; o; o >>= 1) { aS += __shfl_xor(aS, o); rS += __shfl_xor(rS, o); }
            if (t == 0) {
                atomicAdd(&bin[(bid & 63) * 8 + rA], aS);
                atomicAdd(&bin[(bid & 63) * 8 + 4 + rA], rS);
            }
        } else {
            if (in0) {
                atomicAdd(&bin[(bid & 63) * 8 + rr0], att0);
                atomicAdd(&bin[(bid & 63) * 8 + 4 + rr0], rep0);
            }
            if (in1) {
                atomicAdd(&bin[(bid & 63) * 8 + rr1], att1);
                atomicAdd(&bin[(bid & 63) * 8 + 4 + rr1], rep1);
            }
        }
    }
    // last-block finale
    if (t == 0) {
        __threadfence();
        unsigned tkv = atomicAdd(tk, 1u);
        sLast = (tkv == gridDim.x - 1) ? 1 : 0;
    }
    __syncthreads();
    if (sLast) {
        __threadfence();
        __shared__ float sOP[4], sAR[8], sNS[8];
        if (t < 4) sOP[t] = 0.f;
        __syncthreads();
        int s = t & 7, g = t >> 3;
        float a = 0.f, n = 0.f;
#pragma unroll
        for (int m = 0; m < 8; ++m) {
            a += bin[(g + 8 * m) * 8 + s];
            n += wc[W_NS + (g + 8 * m) * 8 + s];
        }
        a += __shfl_xor(a, 8); a += __shfl_xor(a, 16); a += __shfl_xor(a, 32);
        n += __shfl_xor(n, 8); n += __shfl_xor(n, 16); n += __shfl_xor(n, 32);
        if (t < 8) { sAR[t] = a; sNS[t] = n; }
        for (int k = t; k < 1024; k += 64) {
            unsigned cnt = ((const unsigned*)wc)[A_NKM + k];
            if (cnt > 0u) {
                float ls = 0.f;
#pragma unroll
                for (int rp = 0; rp < 8; ++rp) ls += lse[(rp << 10) + k];
                float4 em = ((const float4*)(wc + A_EM))[k];
                float m = fdec(__float_as_uint(em.z));
                float lsev = m + 0.001f * logf(ls + 1e-30f);
                float sbc = fminf(fmaxf(wc[A_SBM + k], 0.f), 1.f);
                atomicAdd(&sOP[k >> 8], (1.f - lsev) + (1.f - sbc));
            }
        }
        __syncthreads();
        if (t == 0) {
            float lv = 0.f, lr = 0.f, lb = 0.f;
            for (int r = 0; r < B_RS; ++r) {
                float len = (float)(rs[r + 1] - rs[r]);
                lv += sAR[r] / len;
                lr += sAR[4 + r] / len;
                float oc = wc[A_OC + r];
                lb += sOP[r] / fmaxf(oc, 1.f) + sNS[2 * r + 1] / fmaxf(sNS[2 * r], 1.f);
            }
            out[0] = lv * 0.25f;
            out[1] = lr * 0.25f;
            out[2] = lb * 0.25f;
        }
    }
}

extern "C" void kernel_launch(void* const* d_in, const int* in_sizes, int n_in,
                              void* d_out, int out_size, void* d_ws, size_t ws_size,
                              hipStream_t stream) {
    const float* beta = (const float*)d_in[0];
    const float* coords = (const float*)d_in[1];
    const int* asso = (const int*)d_in[2];
    const int* rs = (const int*)d_in[3];
    int N = in_sizes[0];
    float* w = (float*)d_ws;
    float* out = (float*)d_out;
    int nb = (N + 127) / 128;
    hipLaunchKernelGGL(k_p1, dim3(NB1), dim3(512), 0, stream, beta, asso, rs, w, N);
    hipLaunchKernelGGL(k_m1, dim3(4), dim3(256), 0, stream, beta, coords, rs, w);
    hipLaunchKernelGGL(k_p4, dim3(nb), dim3(64), 0, stream, beta, coords, asso, rs,
                       w, w + A_LSE, w + A_BIN, (unsigned*)(w + A_TK), out, N);
}

// Round 12
// 69.719 us; speedup vs baseline: 1.5809x; 1.3421x over previous
//
#include <hip/hip_runtime.h>

#define NB1 64
#define B_RS 4

// workspace float offsets
#define W_K    0         // [64][1024] u64 packed (fkey<<32 | idx) -> 131072 slots
#define W_C    131072    // [64][1024] u32 counts
#define W_SB   196608    // [64][1024] f32 sum_b
#define W_SP   262144    // [64][1024] f32 p_sum
#define W_NS   327680    // [64][8] noise (cnt,sum per row)
#define A_CY0  328192    // 1024 float4 (-2x lo)
#define A_CY1  332288    // 1024 float4 (-2x hi)
#define A_LM   336384    // 1024 float2 (ck2+1e-6, cf)
#define A_EM   338432    // 1024 float4 (qa, psum, keym_bits, cf)
#define A_SBM  342528    // 1024 merged sum_b
#define A_NKM  343552    // 1024 u32 merged count
#define A_OC   344576    // 4 obj_cnt per row (+4 pad)
#define A_LSE  344584    // 8 x 1024 LSE slices
#define A_BIN  352776    // 64 reps x 8 row bins (att[4], rep[4])
#define A_TK   353288    // ticket (u32)

__device__ __forceinline__ unsigned fkey(float f) {
    unsigned u = __float_as_uint(f);
    return ((int)u < 0) ? ~u : (u | 0x80000000u);
}
__device__ __forceinline__ float fdec(unsigned k) {
    unsigned u = ((int)k < 0) ? (k & 0x7fffffffu) : ~k;
    return __uint_as_float(u);
}
__device__ __forceinline__ float fsq(float x) { return __builtin_amdgcn_sqrtf(x); }

// ---- P1: block-local LDS aggregation, private-slice flush ----
__global__ __launch_bounds__(512) void k_p1(const float* __restrict__ beta,
                                            const int* __restrict__ asso,
                                            const int* __restrict__ rs,
                                            float* __restrict__ w, int N) {
    __shared__ unsigned long long sk[1024];
    __shared__ unsigned sc[1024];
    __shared__ float ssb[1024], ssp[1024];
    __shared__ float ns[8];
    int t = threadIdx.x, b = blockIdx.x;
    for (int j = t; j < 1024; j += 512) { sk[j] = 0ull; sc[j] = 0u; ssb[j] = 0.f; ssp[j] = 0.f; }
    if (t < 8) ns[t] = 0.f;
    int rs1 = rs[1], rs2 = rs[2], rs3 = rs[3];
    __syncthreads();
    for (int i = b * 512 + t; i < N; i += NB1 * 512) {
        float bv = beta[i];
        int a = asso[i];
        float bc = fminf(fmaxf(bv, 0.f), 0.999f);
        float ath = 0.5f * __logf(__fdividef(1.f + bc, 1.f - bc));
        float at2 = ath * ath;
        float pv = fmaxf(at2, 1e-6f);
        if (a >= 0) {
            unsigned long long pk = (((unsigned long long)fkey(bv)) << 32) | (unsigned)i;
            atomicMax(&sk[a], pk);
            atomicAdd(&sc[a], 1u);
            atomicAdd(&ssb[a], bv);
            atomicAdd(&ssp[a], pv);
        } else {
            int r = (i >= rs1) + (i >= rs2) + (i >= rs3);
            atomicAdd(&ns[2 * r], 1.f);
            atomicAdd(&ns[2 * r + 1], bv);
        }
    }
    __syncthreads();
    for (int j = t; j < 1024; j += 512) {
        ((unsigned long long*)w)[(b << 10) + j] = sk[j];
        ((unsigned*)w)[W_C + (b << 10) + j] = sc[j];
        w[W_SB + (b << 10) + j] = ssb[j];
        w[W_SP + (b << 10) + j] = ssp[j];
    }
    if (t < 8) w[W_NS + b * 8 + t] = ns[t];
}

// ---- M1: merge slices (4 lanes/cluster x 16 slices), finalize, zero LSE/bins ----
__global__ __launch_bounds__(1024) void k_m1(const float* __restrict__ beta,
                                             const float* __restrict__ coords,
                                             const int* __restrict__ rs,
                                             float* __restrict__ w) {
    __shared__ int oc0;
    int t = threadIdx.x, r = blockIdx.x;
    if (t == 0) oc0 = 0;
    int ci = t >> 2, sub = t & 3;
    int k = (r << 8) + ci;
    unsigned long long k64 = 0ull;
    unsigned cnt = 0u;
    float sb = 0.f, sp = 0.f;
#pragma unroll 4
    for (int m = 0; m < 16; ++m) {
        int rp = sub * 16 + m;
        unsigned long long v = ((const unsigned long long*)w)[(rp << 10) + k];
        k64 = v > k64 ? v : k64;
        cnt += ((const unsigned*)w)[W_C + (rp << 10) + k];
        sb += w[W_SB + (rp << 10) + k];
        sp += w[W_SP + (rp << 10) + k];
    }
    // combine 4 adjacent lanes
    {
        unsigned long long o = __shfl_xor(k64, 1); k64 = o > k64 ? o : k64;
        o = __shfl_xor(k64, 2); k64 = o > k64 ? o : k64;
        cnt += __shfl_xor(cnt, 1); cnt += __shfl_xor(cnt, 2);
        sb += __shfl_xor(sb, 1); sb += __shfl_xor(sb, 2);
        sp += __shfl_xor(sp, 1); sp += __shfl_xor(sp, 2);
    }
    bool ov = cnt > 0u;
    if (sub == 0) {
        int ai = (int)(unsigned)(k64 & 0xffffffffull);
        float4 x0 = ((const float4*)coords)[ai * 2];
        float4 x1 = ((const float4*)coords)[ai * 2 + 1];
        float ba = beta[ai];
        float bca = fminf(fmaxf(ba, 0.f), 0.999f);
        float ata = atanhf(bca);
        float qa = ov ? ata * ata + 0.1f : 0.f;
        float cf = qa / fmaxf((float)cnt, 1.f);
        ((float4*)(w + A_CY0))[k] = make_float4(-2.f * x0.x, -2.f * x0.y, -2.f * x0.z, -2.f * x0.w);
        ((float4*)(w + A_CY1))[k] = make_float4(-2.f * x1.x, -2.f * x1.y, -2.f * x1.z, -2.f * x1.w);
        float ck2 = x0.x * x0.x + x0.y * x0.y + x0.z * x0.z + x0.w * x0.w +
                    x1.x * x1.x + x1.y * x1.y + x1.z * x1.z + x1.w * x1.w;
        ((float2*)(w + A_LM))[k] = make_float2(ck2 + 1e-6f, cf);
        ((float4*)(w + A_EM))[k] = make_float4(qa, sp, __uint_as_float((unsigned)(k64 >> 32)), cf);
        w[A_SBM + k] = sb;
        ((unsigned*)w)[A_NKM + k] = cnt;
    }
    for (int j = t; j < 2048; j += 1024) w[A_LSE + (r << 11) + j] = 0.f;
    if (r == 0) {
        if (t < 512) w[A_BIN + t] = 0.f;
        if (t == 0) ((unsigned*)w)[A_TK] = 0u;
    }
    __syncthreads();
    unsigned long long bal = __ballot(ov && sub == 0);
    if ((t & 63) == 0) atomicAdd(&oc0, __popcll(bal));
    __syncthreads();
    if (t == 0) w[A_OC + r] = (float)oc0;
}

// ---- P4: 128-thr blocks, 2pt/thread, full-row stage, fused epilogue + finale ----
__global__ __launch_bounds__(128) void k_p4(const float* __restrict__ beta,
                                            const float* __restrict__ coords,
                                            const int* __restrict__ asso,
                                            const int* __restrict__ rs,
                                            const float* __restrict__ wc,
                                            float* __restrict__ lse,
                                            float* __restrict__ bin,
                                            unsigned* __restrict__ tk,
                                            float* __restrict__ out, int N) {
    __shared__ float4 sY0[512], sY1[512];
    __shared__ float2 sLM[512];
    __shared__ float sOC[4];
    __shared__ float bins[8];
    __shared__ int sLast;
    int t = threadIdx.x, bid = blockIdx.x;
    int base = bid << 8;
    int rs1 = rs[1], rs2 = rs[2], rs3 = rs[3];
    int r0 = (base >= rs1) + (base >= rs2) + (base >= rs3);
    int lastp = min(base + 255, N - 1);
    int rl = (lastp >= rs1) + (lastp >= rs2) + (lastp >= rs3);
    const float4* cy0 = (const float4*)(wc + A_CY0);
    const float4* cy1 = (const float4*)(wc + A_CY1);
    const float2* lmt = (const float2*)(wc + A_LM);
    const float4* emt = (const float4*)(wc + A_EM);
#pragma unroll
    for (int j = t; j < 256; j += 128) {
        int k0 = (r0 << 8) + j;
        sY0[j] = cy0[k0]; sY1[j] = cy1[k0]; sLM[j] = lmt[k0];
    }
    if (rl != r0) {
#pragma unroll
        for (int j = t; j < 256; j += 128) {
            int k1 = (rl << 8) + j;
            sY0[256 + j] = cy0[k1]; sY1[256 + j] = cy1[k1]; sLM[256 + j] = lmt[k1];
        }
    }
    if (t < 4) sOC[t] = wc[A_OC + t];
    if (t < 8) bins[t] = 0.f;
    __syncthreads();
    int i0 = base + 2 * t, i1 = i0 + 1;
    bool in0 = i0 < N, in1 = i1 < N;
    float att0 = 0.f, att1 = 0.f, rep0 = 0.f, rep1 = 0.f;
    int rr0 = r0, rr1 = r0;
    if (in0) {
        const float4* cp = (const float4*)(coords + (size_t)i0 * 8);
        float4 c00 = cp[0], c01 = cp[1], c10, c11;
        float cn20 = c00.x * c00.x + c00.y * c00.y + c00.z * c00.z + c00.w * c00.w +
                     c01.x * c01.x + c01.y * c01.y + c01.z * c01.z + c01.w * c01.w;
        float cn21 = 0.f;
        rr0 = (i0 >= rs1) + (i0 >= rs2) + (i0 >= rs3);
        if (in1) {
            c10 = cp[2]; c11 = cp[3];
            cn21 = c10.x * c10.x + c10.y * c10.y + c10.z * c10.z + c10.w * c10.w +
                   c11.x * c11.x + c11.y * c11.y + c11.z * c11.z + c11.w * c11.w;
            rr1 = (i1 >= rs1) + (i1 >= rs2) + (i1 >= rs3);
        }
        int s0 = (rr0 == r0) ? 0 : 256;
        int s1 = (rr1 == r0) ? 0 : 256;
        float acc0 = 0.f, acc1 = 0.f;
        if (in1 && s0 == s1) {
#pragma unroll 2
            for (int j = s0; j < s0 + 256; ++j) {
                float4 y0 = sY0[j];
                float4 y1 = sY1[j];
                float2 cm = sLM[j];
                float d0 = cn20 + cm.x, d1 = cn21 + cm.x;
                d0 = fmaf(y0.x, c00.x, d0); d1 = fmaf(y0.x, c10.x, d1);
                d0 = fmaf(y0.y, c00.y, d0); d1 = fmaf(y0.y, c10.y, d1);
                d0 = fmaf(y0.z, c00.z, d0); d1 = fmaf(y0.z, c10.z, d1);
                d0 = fmaf(y0.w, c00.w, d0); d1 = fmaf(y0.w, c10.w, d1);
                d0 = fmaf(y1.x, c01.x, d0); d1 = fmaf(y1.x, c11.x, d1);
                d0 = fmaf(y1.y, c01.y, d0); d1 = fmaf(y1.y, c11.y, d1);
                d0 = fmaf(y1.z, c01.z, d0); d1 = fmaf(y1.z, c11.z, d1);
                d0 = fmaf(y1.w, c01.w, d0); d1 = fmaf(y1.w, c11.w, d1);
                d0 = fmaxf(d0, 1e-6f); d1 = fmaxf(d1, 1e-6f);
                float v0 = fmaxf(1.f - fsq(d0), 0.f);
                float v1 = fmaxf(1.f - fsq(d1), 0.f);
                acc0 = fmaf(v0, cm.y, acc0);
                acc1 = fmaf(v1, cm.y, acc1);
            }
        } else {
#pragma unroll 2
            for (int j = s0; j < s0 + 256; ++j) {
                float4 y0 = sY0[j]; float4 y1 = sY1[j]; float2 cm = sLM[j];
                float d = cn20 + cm.x;
                d = fmaf(y0.x, c00.x, d); d = fmaf(y0.y, c00.y, d);
                d = fmaf(y0.z, c00.z, d); d = fmaf(y0.w, c00.w, d);
                d = fmaf(y1.x, c01.x, d); d = fmaf(y1.y, c01.y, d);
                d = fmaf(y1.z, c01.z, d); d = fmaf(y1.w, c01.w, d);
                d = fmaxf(d, 1e-6f);
                acc0 = fmaf(fmaxf(1.f - fsq(d), 0.f), cm.y, acc0);
            }
            if (in1) {
#pragma unroll 2
                for (int j = s1; j < s1 + 256; ++j) {
                    float4 y0 = sY0[j]; float4 y1 = sY1[j]; float2 cm = sLM[j];
                    float d = cn21 + cm.x;
                    d = fmaf(y0.x, c10.x, d); d = fmaf(y0.y, c10.y, d);
                    d = fmaf(y0.z, c10.z, d); d = fmaf(y0.w, c10.w, d);
                    d = fmaf(y1.x, c11.x, d); d = fmaf(y1.y, c11.y, d);
                    d = fmaf(y1.z, c11.z, d); d = fmaf(y1.w, c11.w, d);
                    d = fmaxf(d, 1e-6f);
                    acc1 = fmaf(fmaxf(1.f - fsq(d), 0.f), cm.y, acc1);
                }
            }
        }
        float2 b2; int2 a2;
        if (in1) { b2 = *(const float2*)(beta + i0); a2 = *(const int2*)(asso + i0); }
        else { b2.x = beta[i0]; b2.y = 0.f; a2.x = asso[i0]; a2.y = -1; }
#pragma unroll
        for (int p = 0; p < 2; ++p) {
            if (p && !in1) break;
            int i = p ? i1 : i0;
            float bv = p ? b2.y : b2.x;
            int aa = p ? a2.y : a2.x;
            float acc = p ? acc1 : acc0;
            float4 cA = p ? c10 : c00;
            float4 cB = p ? c11 : c01;
            float cn2 = p ? cn21 : cn20;
            int r = p ? rr1 : rr0;
            float bc = fminf(fmaxf(bv, 0.f), 0.999f);
            float ath = 0.5f * __logf(__fdividef(1.f + bc, 1.f - bc));
            float at2 = ath * ath;
            float q = at2 + 0.1f;
            float attv = 0.f, pl = 0.f;
            if (aa >= 0) {
                // global reads (L2-hot, same bits as staged) -> no LDS gather conflicts
                float4 y0 = cy0[aa], y1 = cy1[aa];
                float2 cm = lmt[aa];
                float4 em = emt[aa];
                float d0 = cA.x + 0.5f * y0.x, d1 = cA.y + 0.5f * y0.y;
                float d2 = cA.z + 0.5f * y0.z, d3 = cA.w + 0.5f * y0.w;
                float d4 = cB.x + 0.5f * y1.x, d5 = cB.y + 0.5f * y1.y;
                float d6 = cB.z + 0.5f * y1.z, d7 = cB.w + 0.5f * y1.w;
                float dsq = d0 * d0 + d1 * d1 + d2 * d2 + d3 * d3 +
                            d4 * d4 + d5 * d5 + d6 * d6 + d7 * d7;
                attv = q * em.x * dsq;
                // own-term: identical instruction sequence to the loop -> exact cancel
                float d = cn2 + cm.x;
                d = fmaf(y0.x, cA.x, d); d = fmaf(y0.y, cA.y, d);
                d = fmaf(y0.z, cA.z, d); d = fmaf(y0.w, cA.w, d);
                d = fmaf(y1.x, cB.x, d); d = fmaf(y1.y, cB.y, d);
                d = fmaf(y1.z, cB.z, d); d = fmaf(y1.w, cB.w, d);
                d = fmaxf(d, 1e-6f);
                acc -= fmaxf(1.f - fsq(d), 0.f) * cm.y;
                float m = fdec(__float_as_uint(em.z));
                atomicAdd(&lse[((bid & 7) << 10) + aa], __expf((bv - m) * 1000.f));
                float pv = fmaxf(at2, 1e-6f);
                pl = pv / fmaxf(em.y, 1e-6f) / fmaxf(sOC[r], 1.f) * 0.25f;
            }
            float repc = q * acc;
            out[3 + i] = pl;
            out[3 + N + i] = attv + repc;
            if (p) { att1 = attv; rep1 = repc; } else { att0 = attv; rep0 = repc; }
        }
    }
    // row-bin reduction (per wave -> LDS -> global replica)
    {
        int rA = __shfl(rr0, 0);
        bool uni = __all(rr0 == rA) && __all(rr1 == rA);
        int lane = t & 63;
        if (uni) {
            float aS = att0 + att1, rS = rep0 + rep1;
#pragma unroll
            for (int o = 32; o; o >>= 1) { aS += __shfl_xor(aS, o); rS += __shfl_xor(rS, o); }
            if (lane == 0) { atomicAdd(&bins[rA], aS); atomicAdd(&bins[4 + rA], rS); }
        } else {
            if (in0) { atomicAdd(&bins[rr0], att0); atomicAdd(&bins[4 + rr0], rep0); }
            if (in1) { atomicAdd(&bins[rr1], att1); atomicAdd(&bins[4 + rr1], rep1); }
        }
    }
    __syncthreads();
    if (t < 8) atomicAdd(&bin[(bid & 63) * 8 + t], bins[t]);
    // last-block finale
    if (t == 0) {
        __threadfence();
        unsigned tkv = atomicAdd(tk, 1u);
        sLast = (tkv == gridDim.x - 1) ? 1 : 0;
    }
    __syncthreads();
    if (sLast) {
        __threadfence();
        __shared__ float sOP[4], sAR[8], sNS[8];
        if (t < 4) sOP[t] = 0.f;
        __syncthreads();
        if (t < 64) {
            int s = t & 7, g = t >> 3;
            float a = 0.f, n = 0.f;
#pragma unroll
            for (int m = 0; m < 8; ++m) {
                a += bin[(g + 8 * m) * 8 + s];
                n += wc[W_NS + (g + 8 * m) * 8 + s];
            }
            a += __shfl_xor(a, 8); a += __shfl_xor(a, 16); a += __shfl_xor(a, 32);
            n += __shfl_xor(n, 8); n += __shfl_xor(n, 16); n += __shfl_xor(n, 32);
            if (t < 8) { sAR[t] = a; sNS[t] = n; }
        }
        for (int k = t; k < 1024; k += 128) {
            unsigned cnt = ((const unsigned*)wc)[A_NKM + k];
            if (cnt > 0u) {
                float ls = 0.f;
#pragma unroll
                for (int rp = 0; rp < 8; ++rp) ls += lse[(rp << 10) + k];
                float4 em = ((const float4*)(wc + A_EM))[k];
                float m = fdec(__float_as_uint(em.z));
                float lsev = m + 0.001f * logf(ls + 1e-30f);
                float sbc = fminf(fmaxf(wc[A_SBM + k], 0.f), 1.f);
                atomicAdd(&sOP[k >> 8], (1.f - lsev) + (1.f - sbc));
            }
        }
        __syncthreads();
        if (t == 0) {
            float lv = 0.f, lr = 0.f, lb = 0.f;
            for (int r = 0; r < B_RS; ++r) {
                float len = (float)(rs[r + 1] - rs[r]);
                lv += sAR[r] / len;
                lr += sAR[4 + r] / len;
                float oc = wc[A_OC + r];
                lb += sOP[r] / fmaxf(oc, 1.f) + sNS[2 * r + 1] / fmaxf(sNS[2 * r], 1.f);
            }
            out[0] = lv * 0.25f;
            out[1] = lr * 0.25f;
            out[2] = lb * 0.25f;
        }
    }
}

extern "C" void kernel_launch(void* const* d_in, const int* in_sizes, int n_in,
                              void* d_out, int out_size, void* d_ws, size_t ws_size,
                              hipStream_t stream) {
    const float* beta = (const float*)d_in[0];
    const float* coords = (const float*)d_in[1];
    const int* asso = (const int*)d_in[2];
    const int* rs = (const int*)d_in[3];
    int N = in_sizes[0];
    float* w = (float*)d_ws;
    float* out = (float*)d_out;
    int nb = (N + 255) / 256;
    hipLaunchKernelGGL(k_p1, dim3(NB1), dim3(512), 0, stream, beta, asso, rs, w, N);
    hipLaunchKernelGGL(k_m1, dim3(4), dim3(1024), 0, stream, beta, coords, rs, w);
    hipLaunchKernelGGL(k_p4, dim3(nb), dim3(128), 0, stream, beta, coords, asso, rs,
                       w, w + A_LSE, w + A_BIN, (unsigned*)(w + A_TK), out, N);
}

// Round 13
// 54.596 us; speedup vs baseline: 2.0188x; 1.2770x over previous
//
#include <hip/hip_runtime.h>

#define NB1 64
#define B_RS 4

// workspace float offsets
#define W_K    0         // [64][1024] u64 packed (fkey<<32 | idx) -> 131072 slots
#define W_C    131072    // [64][1024] u32 counts
#define W_SB   196608    // [64][1024] f32 sum_b
#define W_SP   262144    // [64][1024] f32 p_sum
#define W_NS   327680    // [64][8] noise (cnt,sum per row)
#define A_CY0  328192    // 1024 float4 (-2x lo)
#define A_CY1  332288    // 1024 float4 (-2x hi)
#define A_LM   336384    // 1024 float2 (ck2+1e-6, cf)
#define A_EM   338432    // 1024 float4 (qa, psum, keym_bits, cf)
#define A_SBM  342528    // 1024 merged sum_b
#define A_NKM  343552    // 1024 u32 merged count
#define A_OC   344576    // 4 obj_cnt per row (+4 pad)
#define A_LSE  344584    // 8 x 1024 LSE slices
#define A_BIN  352776    // 64 reps x 8 row bins (att[4], rep[4])
#define A_TK   353288    // ticket (u32)

__device__ __forceinline__ unsigned fkey(float f) {
    unsigned u = __float_as_uint(f);
    return ((int)u < 0) ? ~u : (u | 0x80000000u);
}
__device__ __forceinline__ float fdec(unsigned k) {
    unsigned u = ((int)k < 0) ? (k & 0x7fffffffu) : ~k;
    return __uint_as_float(u);
}
__device__ __forceinline__ float fsq(float x) { return __builtin_amdgcn_sqrtf(x); }

// ---- P1: block-local LDS aggregation, private-slice flush ----
__global__ __launch_bounds__(512) void k_p1(const float* __restrict__ beta,
                                            const int* __restrict__ asso,
                                            const int* __restrict__ rs,
                                            float* __restrict__ w, int N) {
    __shared__ unsigned long long sk[1024];
    __shared__ unsigned sc[1024];
    __shared__ float ssb[1024], ssp[1024];
    __shared__ float ns[8];
    int t = threadIdx.x, b = blockIdx.x;
    for (int j = t; j < 1024; j += 512) { sk[j] = 0ull; sc[j] = 0u; ssb[j] = 0.f; ssp[j] = 0.f; }
    if (t < 8) ns[t] = 0.f;
    int rs1 = rs[1], rs2 = rs[2], rs3 = rs[3];
    __syncthreads();
    for (int i = b * 512 + t; i < N; i += NB1 * 512) {
        float bv = beta[i];
        int a = asso[i];
        float bc = fminf(fmaxf(bv, 0.f), 0.999f);
        float ath = 0.5f * __logf(__fdividef(1.f + bc, 1.f - bc));
        float at2 = ath * ath;
        float pv = fmaxf(at2, 1e-6f);
        if (a >= 0) {
            unsigned long long pk = (((unsigned long long)fkey(bv)) << 32) | (unsigned)i;
            atomicMax(&sk[a], pk);
            atomicAdd(&sc[a], 1u);
            atomicAdd(&ssb[a], bv);
            atomicAdd(&ssp[a], pv);
        } else {
            int r = (i >= rs1) + (i >= rs2) + (i >= rs3);
            atomicAdd(&ns[2 * r], 1.f);
            atomicAdd(&ns[2 * r + 1], bv);
        }
    }
    __syncthreads();
    for (int j = t; j < 1024; j += 512) {
        ((unsigned long long*)w)[(b << 10) + j] = sk[j];
        ((unsigned*)w)[W_C + (b << 10) + j] = sc[j];
        w[W_SB + (b << 10) + j] = ssb[j];
        w[W_SP + (b << 10) + j] = ssp[j];
    }
    if (t < 8) w[W_NS + b * 8 + t] = ns[t];
}

// ---- M1: merge slices (4 lanes/cluster x 16 slices), finalize, zero LSE/bins ----
__global__ __launch_bounds__(1024) void k_m1(const float* __restrict__ beta,
                                             const float* __restrict__ coords,
                                             const int* __restrict__ rs,
                                             float* __restrict__ w) {
    __shared__ int oc0;
    int t = threadIdx.x, r = blockIdx.x;
    if (t == 0) oc0 = 0;
    int ci = t >> 2, sub = t & 3;
    int k = (r << 8) + ci;
    unsigned long long k64 = 0ull;
    unsigned cnt = 0u;
    float sb = 0.f, sp = 0.f;
#pragma unroll 4
    for (int m = 0; m < 16; ++m) {
        int rp = sub * 16 + m;
        unsigned long long v = ((const unsigned long long*)w)[(rp << 10) + k];
        k64 = v > k64 ? v : k64;
        cnt += ((const unsigned*)w)[W_C + (rp << 10) + k];
        sb += w[W_SB + (rp << 10) + k];
        sp += w[W_SP + (rp << 10) + k];
    }
    {
        unsigned long long o = __shfl_xor(k64, 1); k64 = o > k64 ? o : k64;
        o = __shfl_xor(k64, 2); k64 = o > k64 ? o : k64;
        cnt += __shfl_xor(cnt, 1); cnt += __shfl_xor(cnt, 2);
        sb += __shfl_xor(sb, 1); sb += __shfl_xor(sb, 2);
        sp += __shfl_xor(sp, 1); sp += __shfl_xor(sp, 2);
    }
    bool ov = cnt > 0u;
    if (sub == 0) {
        int ai = (int)(unsigned)(k64 & 0xffffffffull);
        float4 x0 = ((const float4*)coords)[ai * 2];
        float4 x1 = ((const float4*)coords)[ai * 2 + 1];
        float ba = beta[ai];
        float bca = fminf(fmaxf(ba, 0.f), 0.999f);
        float ata = atanhf(bca);
        float qa = ov ? ata * ata + 0.1f : 0.f;
        float cf = qa / fmaxf((float)cnt, 1.f);
        ((float4*)(w + A_CY0))[k] = make_float4(-2.f * x0.x, -2.f * x0.y, -2.f * x0.z, -2.f * x0.w);
        ((float4*)(w + A_CY1))[k] = make_float4(-2.f * x1.x, -2.f * x1.y, -2.f * x1.z, -2.f * x1.w);
        float ck2 = x0.x * x0.x + x0.y * x0.y + x0.z * x0.z + x0.w * x0.w +
                    x1.x * x1.x + x1.y * x1.y + x1.z * x1.z + x1.w * x1.w;
        ((float2*)(w + A_LM))[k] = make_float2(ck2 + 1e-6f, cf);
        ((float4*)(w + A_EM))[k] = make_float4(qa, sp, __uint_as_float((unsigned)(k64 >> 32)), cf);
        w[A_SBM + k] = sb;
        ((unsigned*)w)[A_NKM + k] = cnt;
    }
    for (int j = t; j < 2048; j += 1024) w[A_LSE + (r << 11) + j] = 0.f;
    if (r == 0) {
        if (t < 512) w[A_BIN + t] = 0.f;
        if (t == 0) ((unsigned*)w)[A_TK] = 0u;
    }
    __syncthreads();
    unsigned long long bal = __ballot(ov && sub == 0);
    if ((t & 63) == 0) atomicAdd(&oc0, __popcll(bal));
    __syncthreads();
    if (t == 0) w[A_OC + r] = (float)oc0;
}

// ---- P4: 512 thr = 8 waves, cluster-halves split across wave pairs, LDS combine ----
__global__ __launch_bounds__(512) void k_p4(const float* __restrict__ beta,
                                            const float* __restrict__ coords,
                                            const int* __restrict__ asso,
                                            const int* __restrict__ rs,
                                            const float* __restrict__ wc,
                                            float* __restrict__ lse,
                                            float* __restrict__ bin,
                                            unsigned* __restrict__ tk,
                                            float* __restrict__ out, int N) {
    __shared__ float4 sY0[512], sY1[512];
    __shared__ float2 sLM[512];
    __shared__ float sAcc[512];
    __shared__ float sOC[4];
    __shared__ float bins[8];
    __shared__ int sLast;
    int t = threadIdx.x, bid = blockIdx.x;
    int base = bid << 8;
    int rs1 = rs[1], rs2 = rs[2], rs3 = rs[3];
    int r0 = (base >= rs1) + (base >= rs2) + (base >= rs3);
    int lastp = min(base + 255, N - 1);
    int rl = (lastp >= rs1) + (lastp >= rs2) + (lastp >= rs3);
    const float4* cy0 = (const float4*)(wc + A_CY0);
    const float4* cy1 = (const float4*)(wc + A_CY1);
    const float2* lmt = (const float2*)(wc + A_LM);
    const float4* emt = (const float4*)(wc + A_EM);
    if (t < 256) {
        int k0 = (r0 << 8) + t;
        sY0[t] = cy0[k0]; sY1[t] = cy1[k0]; sLM[t] = lmt[k0];
    } else if (rl != r0) {
        int k1 = (rl << 8) + (t - 256);
        sY0[t] = cy0[k1]; sY1[t] = cy1[k1]; sLM[t] = lmt[k1];
    }
    if (t < 4) sOC[t] = wc[A_OC + t];
    if (t < 8) bins[t] = 0.f;
    __syncthreads();
    int pi = t & 255, half = t >> 8;
    int i = base + pi;
    bool in = i < N;
    float acc = 0.f;
    int r = r0;
    float4 c0, c1;
    float cn2 = 0.f;
    if (in) {
        const float4* cp = (const float4*)(coords + (size_t)i * 8);
        c0 = cp[0]; c1 = cp[1];
        cn2 = c0.x * c0.x + c0.y * c0.y + c0.z * c0.z + c0.w * c0.w +
              c1.x * c1.x + c1.y * c1.y + c1.z * c1.z + c1.w * c1.w;
        r = (i >= rs1) + (i >= rs2) + (i >= rs3);
        int s = (r == r0) ? 0 : 256;
        int js = s + half * 128, je = js + 128;
#pragma unroll 4
        for (int j = js; j < je; ++j) {
            float4 y0 = sY0[j];
            float4 y1 = sY1[j];
            float2 cm = sLM[j];
            float d = cn2 + cm.x;
            d = fmaf(y0.x, c0.x, d); d = fmaf(y0.y, c0.y, d);
            d = fmaf(y0.z, c0.z, d); d = fmaf(y0.w, c0.w, d);
            d = fmaf(y1.x, c1.x, d); d = fmaf(y1.y, c1.y, d);
            d = fmaf(y1.z, c1.z, d); d = fmaf(y1.w, c1.w, d);
            d = fmaxf(d, 1e-6f);
            float v = fmaxf(1.f - fsq(d), 0.f);
            acc = fmaf(v, cm.y, acc);
        }
    }
    sAcc[t] = acc;
    __syncthreads();
    float att = 0.f, rep = 0.f;
    if (t < 256 && in) {
        float total = sAcc[t] + sAcc[t + 256];
        float bv = beta[i];
        int aa = asso[i];
        float bc = fminf(fmaxf(bv, 0.f), 0.999f);
        float ath = 0.5f * __logf(__fdividef(1.f + bc, 1.f - bc));
        float at2 = ath * ath;
        float q = at2 + 0.1f;
        float pl = 0.f;
        if (aa >= 0) {
            float4 y0 = cy0[aa], y1 = cy1[aa];
            float2 cm = lmt[aa];
            float4 em = emt[aa];
            float d0 = c0.x + 0.5f * y0.x, d1 = c0.y + 0.5f * y0.y;
            float d2 = c0.z + 0.5f * y0.z, d3 = c0.w + 0.5f * y0.w;
            float d4 = c1.x + 0.5f * y1.x, d5 = c1.y + 0.5f * y1.y;
            float d6 = c1.z + 0.5f * y1.z, d7 = c1.w + 0.5f * y1.w;
            float dsq = d0 * d0 + d1 * d1 + d2 * d2 + d3 * d3 +
                        d4 * d4 + d5 * d5 + d6 * d6 + d7 * d7;
            att = q * em.x * dsq;
            // own-term: identical instruction sequence to the loop -> exact cancel
            float d = cn2 + cm.x;
            d = fmaf(y0.x, c0.x, d); d = fmaf(y0.y, c0.y, d);
            d = fmaf(y0.z, c0.z, d); d = fmaf(y0.w, c0.w, d);
            d = fmaf(y1.x, c1.x, d); d = fmaf(y1.y, c1.y, d);
            d = fmaf(y1.z, c1.z, d); d = fmaf(y1.w, c1.w, d);
            d = fmaxf(d, 1e-6f);
            total -= fmaxf(1.f - fsq(d), 0.f) * cm.y;
            float m = fdec(__float_as_uint(em.z));
            atomicAdd(&lse[((bid & 7) << 10) + aa], __expf((bv - m) * 1000.f));
            float pv = fmaxf(at2, 1e-6f);
            pl = pv / fmaxf(em.y, 1e-6f) / fmaxf(sOC[r], 1.f) * 0.25f;
        }
        rep = q * total;
        out[3 + i] = pl;
        out[3 + N + i] = att + rep;
    }
    // row-bin reduction (waves 0-3 only; 1 pt per lane)
    if (t < 256) {
        int rA = __shfl(r, 0);
        bool uni = __all(r == rA);
        int lane = t & 63;
        if (uni) {
            float aS = att, rS = rep;
#pragma unroll
            for (int o = 32; o; o >>= 1) { aS += __shfl_xor(aS, o); rS += __shfl_xor(rS, o); }
            if (lane == 0) { atomicAdd(&bins[rA], aS); atomicAdd(&bins[4 + rA], rS); }
        } else if (in) {
            atomicAdd(&bins[r], att);
            atomicAdd(&bins[4 + r], rep);
        }
    }
    __syncthreads();
    if (t < 8) atomicAdd(&bin[(bid & 63) * 8 + t], bins[t]);
    // last-block finale
    if (t == 0) {
        __threadfence();
        unsigned tkv = atomicAdd(tk, 1u);
        sLast = (tkv == gridDim.x - 1) ? 1 : 0;
    }
    __syncthreads();
    if (sLast) {
        __threadfence();
        __shared__ float sOP[4], sAR[8], sNS[8];
        if (t < 4) sOP[t] = 0.f;
        __syncthreads();
        if (t < 64) {
            int s = t & 7, g = t >> 3;
            float a = 0.f, n = 0.f;
#pragma unroll
            for (int m = 0; m < 8; ++m) {
                a += bin[(g + 8 * m) * 8 + s];
                n += wc[W_NS + (g + 8 * m) * 8 + s];
            }
            a += __shfl_xor(a, 8); a += __shfl_xor(a, 16); a += __shfl_xor(a, 32);
            n += __shfl_xor(n, 8); n += __shfl_xor(n, 16); n += __shfl_xor(n, 32);
            if (t < 8) { sAR[t] = a; sNS[t] = n; }
        }
        for (int k = t; k < 1024; k += 512) {
            unsigned cnt = ((const unsigned*)wc)[A_NKM + k];
            if (cnt > 0u) {
                float ls = 0.f;
#pragma unroll
                for (int rp = 0; rp < 8; ++rp) ls += lse[(rp << 10) + k];
                float4 em = ((const float4*)(wc + A_EM))[k];
                float m = fdec(__float_as_uint(em.z));
                float lsev = m + 0.001f * logf(ls + 1e-30f);
                float sbc = fminf(fmaxf(wc[A_SBM + k], 0.f), 1.f);
                atomicAdd(&sOP[k >> 8], (1.f - lsev) + (1.f - sbc));
            }
        }
        __syncthreads();
        if (t == 0) {
            float lv = 0.f, lr = 0.f, lb = 0.f;
            for (int r2 = 0; r2 < B_RS; ++r2) {
                float len = (float)(rs[r2 + 1] - rs[r2]);
                lv += sAR[r2] / len;
                lr += sAR[4 + r2] / len;
                float oc = wc[A_OC + r2];
                lb += sOP[r2] / fmaxf(oc, 1.f) + sNS[2 * r2 + 1] / fmaxf(sNS[2 * r2], 1.f);
            }
            out[0] = lv * 0.25f;
            out[1] = lr * 0.25f;
            out[2] = lb * 0.25f;
        }
    }
}

extern "C" void kernel_launch(void* const* d_in, const int* in_sizes, int n_in,
                              void* d_out, int out_size, void* d_ws, size_t ws_size,
                              hipStream_t stream) {
    const float* beta = (const float*)d_in[0];
    const float* coords = (const float*)d_in[1];
    const int* asso = (const int*)d_in[2];
    const int* rs = (const int*)d_in[3];
    int N = in_sizes[0];
    float* w = (float*)d_ws;
    float* out = (float*)d_out;
    int nb = (N + 255) / 256;
    hipLaunchKernelGGL(k_p1, dim3(NB1), dim3(512), 0, stream, beta, asso, rs, w, N);
    hipLaunchKernelGGL(k_m1, dim3(4), dim3(1024), 0, stream, beta, coords, rs, w);
    hipLaunchKernelGGL(k_p4, dim3(nb), dim3(512), 0, stream, beta, coords, asso, rs,
                       w, w + A_LSE, w + A_BIN, (unsigned*)(w + A_TK), out, N);
}